// Round 26
// baseline (101.602 us; speedup 1.0000x reference)
//
#include <hip/hip_runtime.h>

// TurboQuantKVCache -- Round 26: bf16-B in LDS, staged in halves (bit-exact).
// R25 (reg prefetch) regressed twice -> reverted; R24 = base (93.2us).
// R24 counter arithmetic: GEMM LDS = 320 b128/wave -> ~51us/CU of LDS pipe
// (> ~42us VALU) -- LDS throughput is the co-bottleneck. Fix: B as bf16 in
// LDS -> ONE ds_read_b128 per kk (16B) + 8 unpack ops. LDS/CU 51->31us for
// +7us VALU. bf16 rows = 256B span for 16 lanes -> conflict-free, no split.
// Staged in 2 HALVES (16KB, 4 barriers total -- R22: barriers cost). LDS
// ~36.3KB -> 4 blk/CU kept. Truncating f32-upcast-bf16 to bf16 is exact and
// unpack restores identical bits -> every FMA operand/order unchanged.
// Predicted: conflicts <0.3M, VALU 77-83%, bench 80-87us, absmax 0.0.

#define TQ_ROWS 64
#define TQ_XPAD 136

__device__ __forceinline__ unsigned short tq_f2bf(float f) {
  unsigned int u = __float_as_uint(f);
  u += 0x7FFFu + ((u >> 16) & 1u);   // round-to-nearest-even
  return (unsigned short)(u >> 16);
}
__device__ __forceinline__ float tq_bf2f(unsigned short h) {
  return __uint_as_float(((unsigned int)h) << 16);
}
__device__ __forceinline__ float tq_lo2f(unsigned int w) {
  return __uint_as_float(w << 16);
}
__device__ __forceinline__ float tq_hi2f(unsigned int w) {
  return __uint_as_float(w & 0xFFFF0000u);
}

__global__ __launch_bounds__(256, 4) void TurboQuantKVCache_85942295593389_kernel(
    const float* __restrict__ kval, const float* __restrict__ vval,
    const int* __restrict__ ipos, const float* __restrict__ rotT,
    const float* __restrict__ bnd, float* __restrict__ out)
{
  __shared__ unsigned short Bh[64 * 128];         // 16 KB bf16 B half [k][c]
  __shared__ unsigned short xs[TQ_ROWS][TQ_XPAD]; // 17.4 KB bf16 rows
  __shared__ float pr[TQ_ROWS][9];                // 2.3 KB norm partials
  __shared__ float nplus[TQ_ROWS];

  const int tid = threadIdx.x;
  const int bid = blockIdx.x;

  const size_t PK = 16777216u;   // k_packed f32 elems
  const size_t NK = 262144u;     // k_norms  f32 elems

  // ---- tail zeroing (f32 rows 4096..16383 of all four outputs) ----
  {
    const uint4 z4 = make_uint4(0u, 0u, 0u, 0u);
    const unsigned gtid = (unsigned)bid * 256u + (unsigned)tid;
    const unsigned gstr = 2048u * 256u;
    for (unsigned z = gtid; z < 6291456u; z += gstr) {   // 12 iters
      const unsigned t = z / 196608u;
      const unsigned rem = z % 196608u;
      uint4* base = (uint4*)(out + ((t >> 4) ? (PK + NK) : (size_t)0) +
                             (size_t)(t & 15) * 1048576u + 262144u);
      base[rem] = z4;
    }
    for (unsigned z = gtid; z < 98304u; z += gstr) {
      const unsigned t = z / 3072u;
      const unsigned rem = z % 3072u;
      uint4* base = (uint4*)(out + ((t >> 4) ? (2 * PK + NK) : PK) +
                             (size_t)(t & 15) * 16384u + 4096u);
      base[rem] = z4;
    }
  }

  // ---- boundaries (f32, bf16-exact) ----
  float bv[15];
#pragma unroll
  for (int q = 0; q < 15; ++q) bv[q] = bnd[q];

  // ---- block -> 64 rows of k or v ----
  const int kv = bid >> 10;                  // 1024 blocks per source
  const int rb = (bid & 1023) * TQ_ROWS;
  const float* src = kv ? vval : kval;
  float* pk = out + (kv ? (PK + NK) : (size_t)0);
  float* pn = out + (kv ? (2 * PK + NK) : PK);

  // ---- stage 64 rows, snap to bf16: 2048 float4, 8 per thread ----
  {
#pragma unroll
    for (int j = 0; j < 8; ++j) {
      const int idx = tid + j * 256;
      const int r = idx >> 5;              // 32 float4 per row
      const int k0 = (idx & 31) << 2;
      const float4 v = *(const float4*)(src + (size_t)(rb + r) * 128 + k0);
      ushort4 w;
      w.x = tq_f2bf(v.x);
      w.y = tq_f2bf(v.y);
      w.z = tq_f2bf(v.z);
      w.w = tq_f2bf(v.w);
      *(ushort4*)&xs[r][k0] = w;
    }
  }
  __syncthreads();

  // ---- norm partials: 8 threads/row, exact r8[j] strided chains ----
  {
    const int j = tid & 7;
    const int rr0 = tid >> 3;              // 0..31
#pragma unroll
    for (int half = 0; half < 2; ++half) {
      const int r = rr0 + half * 32;
      float v = tq_bf2f(xs[r][j]);
      float c = __fmul_rn(v, v);
#pragma unroll
      for (int i = 1; i < 16; ++i) {
        v = tq_bf2f(xs[r][i * 8 + j]);
        c = __fadd_rn(c, __fmul_rn(v, v));
      }
      pr[r][j] = c;
    }
  }
  __syncthreads();

  // ---- pairwise combine + norm store (1 thread/row) ----
  if (tid < TQ_ROWS) {
    const int r = tid;
    const float ss = __fadd_rn(
        __fadd_rn(__fadd_rn(pr[r][0], pr[r][1]), __fadd_rn(pr[r][2], pr[r][3])),
        __fadd_rn(__fadd_rn(pr[r][4], pr[r][5]), __fadd_rn(pr[r][6], pr[r][7])));
    const float nrm = __fsqrt_rn(ss);
    const unsigned short nb = tq_f2bf(nrm);
    nplus[r] = tq_bf2f(tq_f2bf(__fadd_rn(tq_bf2f(nb), tq_bf2f(tq_f2bf(1e-10f)))));
    const int rg = rb + r;
    const int h = rg >> 12, t = rg & 4095;
    pn[(size_t)h * 16384 + ipos[t]] = tq_bf2f(nb);
  }
  __syncthreads();

  // ---- normalize in place ----
  for (int i = tid; i < TQ_ROWS * 128; i += 256) {
    const int r = i >> 7, k = i & 127;
    xs[r][k] = tq_f2bf(__fdiv_rn(tq_bf2f(xs[r][k]), nplus[r]));
  }

  // ---- GEMM: 4 rows x 8 cols/thread; B bf16 via 2 LDS half-stages ----
  const int c0 = (tid & 15) << 3;
  const int r0 = (tid >> 4) << 2;
  const float4* rb4 = (const float4*)rotT;   // 4096 float4 total
  float acc[4][8];
#pragma unroll
  for (int rr = 0; rr < 4; ++rr)
#pragma unroll
    for (int j = 0; j < 8; ++j) acc[rr][j] = 0.f;

  for (int ph = 0; ph < 2; ++ph) {
    __syncthreads();   // prior phase reads done (covers normalize for ph=0)
    // stage 64 B k-rows f32 -> bf16 (truncate, exact): 1024 uint4, 4/thread
    {
#pragma unroll
      for (int j = 0; j < 4; ++j) {
        const int i = tid + j * 256;           // uint4 output index 0..1023
        const float4 v0 = rb4[ph * 2048 + 2 * i];
        const float4 v1 = rb4[ph * 2048 + 2 * i + 1];
        uint4 w;
        w.x = (__float_as_uint(v0.x) >> 16) | (__float_as_uint(v0.y) & 0xFFFF0000u);
        w.y = (__float_as_uint(v0.z) >> 16) | (__float_as_uint(v0.w) & 0xFFFF0000u);
        w.z = (__float_as_uint(v1.x) >> 16) | (__float_as_uint(v1.y) & 0xFFFF0000u);
        w.w = (__float_as_uint(v1.z) >> 16) | (__float_as_uint(v1.w) & 0xFFFF0000u);
        *(uint4*)&Bh[i * 8] = w;
      }
    }
    __syncthreads();

    const int kbase = ph * 64;
    for (int kb = 0; kb < 64; kb += 8) {
      uint4 aw[4];
#pragma unroll
      for (int rr = 0; rr < 4; ++rr)
        aw[rr] = *(const uint4*)&xs[r0 + rr][kbase + kb];
#pragma unroll
      for (int kk = 0; kk < 8; ++kk) {
        const uint4 bw = *(const uint4*)&Bh[(kb + kk) * 128 + c0];
        const float b0 = tq_lo2f(bw.x), b1 = tq_hi2f(bw.x);
        const float b2 = tq_lo2f(bw.y), b3 = tq_hi2f(bw.y);
        const float b4 = tq_lo2f(bw.z), b5 = tq_hi2f(bw.z);
        const float b6 = tq_lo2f(bw.w), b7 = tq_hi2f(bw.w);
#pragma unroll
        for (int rr = 0; rr < 4; ++rr) {
          const unsigned int word = ((const unsigned int*)&aw[rr])[kk >> 1];
          const float a = (kk & 1) ? tq_hi2f(word) : tq_lo2f(word);
          acc[rr][0] = fmaf(a, b0, acc[rr][0]);
          acc[rr][1] = fmaf(a, b1, acc[rr][1]);
          acc[rr][2] = fmaf(a, b2, acc[rr][2]);
          acc[rr][3] = fmaf(a, b3, acc[rr][3]);
          acc[rr][4] = fmaf(a, b4, acc[rr][4]);
          acc[rr][5] = fmaf(a, b5, acc[rr][5]);
          acc[rr][6] = fmaf(a, b6, acc[rr][6]);
          acc[rr][7] = fmaf(a, b7, acc[rr][7]);
        }
      }
    }
  }

  // ---- bucketize (strict <, f32 on bf16-snapped) + pack + f32 store ----
#pragma unroll
  for (int rr = 0; rr < 4; ++rr) {
    int idx[8];
#pragma unroll
    for (int j = 0; j < 8; ++j) {
      const float v = tq_bf2f(tq_f2bf(acc[rr][j]));
      int c = 0;
#pragma unroll
      for (int q = 0; q < 15; ++q) c += (bv[q] < v) ? 1 : 0;
      idx[j] = c;
    }
    const int rg = rb + r0 + rr;
    const int h = rg >> 12, t = rg & 4095;
    float* dst = pk + ((size_t)h * 16384 + ipos[t]) * 64 + (c0 >> 1);
    float4 wv;
    wv.x = (float)((idx[0] << 4) | idx[1]);
    wv.y = (float)((idx[2] << 4) | idx[3]);
    wv.z = (float)((idx[4] << 4) | idx[5]);
    wv.w = (float)((idx[6] << 4) | idx[7]);
    *(float4*)dst = wv;
  }
}

extern "C" void kernel_launch(void* const* d_in, const int* in_sizes, int n_in,
                              void* d_out, int out_size, void* d_ws, size_t ws_size,
                              hipStream_t stream) {
  const int*   ipos = (const int*)d_in[0];
  const float* kval = (const float*)d_in[1];
  const float* vval = (const float*)d_in[2];
  const float* rotT = (const float*)d_in[3];   // bf16 values upcast to f32
  const float* bnd  = (const float*)d_in[4];   // bf16 values upcast to f32
  float* out = (float*)d_out;

  TurboQuantKVCache_85942295593389_kernel<<<dim3(2048), dim3(256), 0, stream>>>(
      kval, vval, ipos, rotT, bnd, out);
}

// Round 27
// 92.764 us; speedup vs baseline: 1.0953x; 1.0953x over previous
//
#include <hip/hip_runtime.h>

// TurboQuantKVCache -- Round 27: FINAL -- resubmit R24 (best: 93.2us).
// R26 post-mortem: conflicts 1.08M->32K as predicted, but dur worsened --
// LDS pipe was already hidden; the bf16-B unpack added pure VALU-issue cost.
// Lever table: occupancy up (R22) worse; reg-prefetch (R23/R25) worse;
// split-B conflict fix (R24) +2% best; LDS-traffic down via bf16-B (R26)
// worse. The gate is VALU issue on the exact-semantics FMA chains
// (single-accumulator ascending-k per output; MFMA/re-association forbidden
// by the 5.1-absmax / high-nibble-16 constraint). R24 = empirical optimum.
// Structure: 64 rows/block, 4 rows x 8 cols/thread, B f32 in split LDS
// (even/odd float4 arrays -> 2-way-free b128 reads), 4 quarter-stages,
// np-pairwise norm via 8 threads/row partials, strict-< f32 bucketize,
// in-kernel f32 tail zeroing. absmax 0.0 (bit-exact vs np reference).

#define TQ_ROWS 64
#define TQ_XPAD 136

__device__ __forceinline__ unsigned short tq_f2bf(float f) {
  unsigned int u = __float_as_uint(f);
  u += 0x7FFFu + ((u >> 16) & 1u);   // round-to-nearest-even
  return (unsigned short)(u >> 16);
}
__device__ __forceinline__ float tq_bf2f(unsigned short h) {
  return __uint_as_float(((unsigned int)h) << 16);
}
__device__ __forceinline__ float tq_lo2f(unsigned int w) {
  return __uint_as_float(w << 16);
}
__device__ __forceinline__ float tq_hi2f(unsigned int w) {
  return __uint_as_float(w & 0xFFFF0000u);
}

__global__ __launch_bounds__(256, 4) void TurboQuantKVCache_85942295593389_kernel(
    const float* __restrict__ kval, const float* __restrict__ vval,
    const int* __restrict__ ipos, const float* __restrict__ rotT,
    const float* __restrict__ bnd, float* __restrict__ out)
{
  __shared__ float Bq0[32 * 64];                  // 8 KB: even float4s (b0)
  __shared__ float Bq1[32 * 64];                  // 8 KB: odd  float4s (b1)
  __shared__ unsigned short xs[TQ_ROWS][TQ_XPAD]; // 17.4 KB bf16 rows
  __shared__ float pr[TQ_ROWS][9];                // 2.3 KB norm partials
  __shared__ float nplus[TQ_ROWS];

  const int tid = threadIdx.x;
  const int bid = blockIdx.x;

  const size_t PK = 16777216u;   // k_packed f32 elems
  const size_t NK = 262144u;     // k_norms  f32 elems

  // ---- tail zeroing (f32 rows 4096..16383 of all four outputs) ----
  {
    const uint4 z4 = make_uint4(0u, 0u, 0u, 0u);
    const unsigned gtid = (unsigned)bid * 256u + (unsigned)tid;
    const unsigned gstr = 2048u * 256u;
    for (unsigned z = gtid; z < 6291456u; z += gstr) {   // 12 iters
      const unsigned t = z / 196608u;
      const unsigned rem = z % 196608u;
      uint4* base = (uint4*)(out + ((t >> 4) ? (PK + NK) : (size_t)0) +
                             (size_t)(t & 15) * 1048576u + 262144u);
      base[rem] = z4;
    }
    for (unsigned z = gtid; z < 98304u; z += gstr) {
      const unsigned t = z / 3072u;
      const unsigned rem = z % 3072u;
      uint4* base = (uint4*)(out + ((t >> 4) ? (2 * PK + NK) : PK) +
                             (size_t)(t & 15) * 16384u + 4096u);
      base[rem] = z4;
    }
  }

  // ---- boundaries (f32, bf16-exact) ----
  float bv[15];
#pragma unroll
  for (int q = 0; q < 15; ++q) bv[q] = bnd[q];

  // ---- block -> 64 rows of k or v ----
  const int kv = bid >> 10;                  // 1024 blocks per source
  const int rb = (bid & 1023) * TQ_ROWS;
  const float* src = kv ? vval : kval;
  float* pk = out + (kv ? (PK + NK) : (size_t)0);
  float* pn = out + (kv ? (2 * PK + NK) : PK);

  // ---- stage 64 rows, snap to bf16: 2048 float4, 8 per thread ----
  {
#pragma unroll
    for (int j = 0; j < 8; ++j) {
      const int idx = tid + j * 256;
      const int r = idx >> 5;              // 32 float4 per row
      const int k0 = (idx & 31) << 2;
      const float4 v = *(const float4*)(src + (size_t)(rb + r) * 128 + k0);
      ushort4 w;
      w.x = tq_f2bf(v.x);
      w.y = tq_f2bf(v.y);
      w.z = tq_f2bf(v.z);
      w.w = tq_f2bf(v.w);
      *(ushort4*)&xs[r][k0] = w;
    }
  }
  __syncthreads();

  // ---- norm partials: 8 threads/row, exact r8[j] strided chains ----
  {
    const int j = tid & 7;
    const int rr0 = tid >> 3;              // 0..31
#pragma unroll
    for (int half = 0; half < 2; ++half) {
      const int r = rr0 + half * 32;
      float v = tq_bf2f(xs[r][j]);
      float c = __fmul_rn(v, v);
#pragma unroll
      for (int i = 1; i < 16; ++i) {
        v = tq_bf2f(xs[r][i * 8 + j]);
        c = __fadd_rn(c, __fmul_rn(v, v));
      }
      pr[r][j] = c;
    }
  }
  __syncthreads();

  // ---- pairwise combine + norm store (1 thread/row) ----
  if (tid < TQ_ROWS) {
    const int r = tid;
    const float ss = __fadd_rn(
        __fadd_rn(__fadd_rn(pr[r][0], pr[r][1]), __fadd_rn(pr[r][2], pr[r][3])),
        __fadd_rn(__fadd_rn(pr[r][4], pr[r][5]), __fadd_rn(pr[r][6], pr[r][7])));
    const float nrm = __fsqrt_rn(ss);
    const unsigned short nb = tq_f2bf(nrm);
    nplus[r] = tq_bf2f(tq_f2bf(__fadd_rn(tq_bf2f(nb), tq_bf2f(tq_f2bf(1e-10f)))));
    const int rg = rb + r;
    const int h = rg >> 12, t = rg & 4095;
    pn[(size_t)h * 16384 + ipos[t]] = tq_bf2f(nb);
  }
  __syncthreads();

  // ---- normalize in place ----
  for (int i = tid; i < TQ_ROWS * 128; i += 256) {
    const int r = i >> 7, k = i & 127;
    xs[r][k] = tq_f2bf(__fdiv_rn(tq_bf2f(xs[r][k]), nplus[r]));
  }

  // ---- GEMM: 4 rows x 8 cols/thread; B via split LDS quarter-stages ----
  const int c0 = (tid & 15) << 3;
  const int r0 = (tid >> 4) << 2;
  const int cj = tid & 15;                   // float4 index within split row
  const float4* rb4 = (const float4*)rotT;   // 4096 float4 total
  float acc[4][8];
#pragma unroll
  for (int rr = 0; rr < 4; ++rr)
#pragma unroll
    for (int j = 0; j < 8; ++j) acc[rr][j] = 0.f;

  for (int ph = 0; ph < 4; ++ph) {
    __syncthreads();   // prior phase reads done (covers normalize for ph=0)
#pragma unroll
    for (int j = 0; j < 4; ++j) {
      const int i = tid + j * 256;           // i = k*32 + c4 (c4 = 0..31)
      const float4 v = rb4[ph * 1024 + i];
      const int k = i >> 5;
      const int c4 = i & 31;
      float4* dst = (c4 & 1) ? (float4*)Bq1 : (float4*)Bq0;
      dst[k * 16 + (c4 >> 1)] = v;
    }
    __syncthreads();

    const int kbase = ph * 32;
    for (int kb = 0; kb < 32; kb += 8) {
      uint4 aw[4];
#pragma unroll
      for (int rr = 0; rr < 4; ++rr)
        aw[rr] = *(const uint4*)&xs[r0 + rr][kbase + kb];
#pragma unroll
      for (int kk = 0; kk < 8; ++kk) {
        const float4 b0 = ((const float4*)Bq0)[(kb + kk) * 16 + cj];
        const float4 b1 = ((const float4*)Bq1)[(kb + kk) * 16 + cj];
#pragma unroll
        for (int rr = 0; rr < 4; ++rr) {
          const unsigned int word = ((const unsigned int*)&aw[rr])[kk >> 1];
          const float a = (kk & 1) ? tq_hi2f(word) : tq_lo2f(word);
          acc[rr][0] = fmaf(a, b0.x, acc[rr][0]);
          acc[rr][1] = fmaf(a, b0.y, acc[rr][1]);
          acc[rr][2] = fmaf(a, b0.z, acc[rr][2]);
          acc[rr][3] = fmaf(a, b0.w, acc[rr][3]);
          acc[rr][4] = fmaf(a, b1.x, acc[rr][4]);
          acc[rr][5] = fmaf(a, b1.y, acc[rr][5]);
          acc[rr][6] = fmaf(a, b1.z, acc[rr][6]);
          acc[rr][7] = fmaf(a, b1.w, acc[rr][7]);
        }
      }
    }
  }

  // ---- bucketize (strict <, f32 on bf16-snapped) + pack + f32 store ----
#pragma unroll
  for (int rr = 0; rr < 4; ++rr) {
    int idx[8];
#pragma unroll
    for (int j = 0; j < 8; ++j) {
      const float v = tq_bf2f(tq_f2bf(acc[rr][j]));
      int c = 0;
#pragma unroll
      for (int q = 0; q < 15; ++q) c += (bv[q] < v) ? 1 : 0;
      idx[j] = c;
    }
    const int rg = rb + r0 + rr;
    const int h = rg >> 12, t = rg & 4095;
    float* dst = pk + ((size_t)h * 16384 + ipos[t]) * 64 + (c0 >> 1);
    float4 wv;
    wv.x = (float)((idx[0] << 4) | idx[1]);
    wv.y = (float)((idx[2] << 4) | idx[3]);
    wv.z = (float)((idx[4] << 4) | idx[5]);
    wv.w = (float)((idx[6] << 4) | idx[7]);
    *(float4*)dst = wv;
  }
}

extern "C" void kernel_launch(void* const* d_in, const int* in_sizes, int n_in,
                              void* d_out, int out_size, void* d_ws, size_t ws_size,
                              hipStream_t stream) {
  const int*   ipos = (const int*)d_in[0];
  const float* kval = (const float*)d_in[1];
  const float* vval = (const float*)d_in[2];
  const float* rotT = (const float*)d_in[3];   // bf16 values upcast to f32
  const float* bnd  = (const float*)d_in[4];   // bf16 values upcast to f32
  float* out = (float*)d_out;

  TurboQuantKVCache_85942295593389_kernel<<<dim3(2048), dim3(256), 0, stream>>>(
      kval, vval, ipos, rotT, bnd, out);
}